// Round 5
// baseline (1147.517 us; speedup 1.0000x reference)
//
#include <hip/hip_runtime.h>

#define PI_F 3.14159265358979f
#define MT 16384   // B*T
#define EE 1024    // E
#define FF 4096    // 4E
#define NCH 8      // T-chunks for kv partial reduction
#define CHT (4096 / NCH)

typedef unsigned short u16;
typedef __attribute__((ext_vector_type(8))) short short8;
typedef __attribute__((ext_vector_type(4))) float f32x4;

__device__ __forceinline__ float bf2f(u16 u) {
  unsigned int v = ((unsigned int)u) << 16;
  float f;
  __builtin_memcpy(&f, &v, 4);
  return f;
}
__device__ __forceinline__ u16 f2bf(float f) {
  unsigned int x;
  __builtin_memcpy(&x, &f, 4);
  unsigned int r = x + 0x7fffu + ((x >> 16) & 1u);
  return (u16)(r >> 16);
}
// load element i from an external buffer whose dtype is runtime-detected
__device__ __forceinline__ float ldin(const void* p, long i, int f32) {
  return f32 ? ((const float*)p)[i] : bf2f(((const u16*)p)[i]);
}
// async global->LDS, 16B/lane; LDS dest = wave-uniform base + lane*16B
__device__ __forceinline__ void async16(const u16* g, u16* l) {
  __builtin_amdgcn_global_load_lds(
      (const __attribute__((address_space(1))) unsigned int*)g,
      (__attribute__((address_space(3))) unsigned int*)l, 16, 0, 0);
}

// ---------------------------------------------------------------------------
// dtype probe: bf16 N(0,1) data has no extreme-exponent u16s; fp32 data's low
// mantissa halves are ~uniform u16s -> ~45% extreme. flag: 0=bf16, 1=fp32.
// ---------------------------------------------------------------------------
__global__ __launch_bounds__(256) void detect_dtype(const u16* __restrict__ x,
                                                    int* __restrict__ flag) {
  const int tid = threadIdx.x;
  int cnt = 0;
  for (int i = tid; i < 2048; i += 256) {
    const int e = (x[i] >> 7) & 0xFF;
    if (e == 0 || e >= 0x90) cnt++;
  }
#pragma unroll
  for (int o = 32; o > 0; o >>= 1) cnt += __shfl_xor(cnt, o);
  __shared__ int s[4];
  if ((tid & 63) == 0) s[tid >> 6] = cnt;
  __syncthreads();
  if (tid == 0) flag[0] = (s[0] + s[1] + s[2] + s[3] > 200) ? 1 : 0;
}

// ---------------------------------------------------------------------------
// transpose + convert external weight: src[R][C] (bf16/f32 per flag) ->
// dst[C][R] bf16. block 256, grid (C/64, R/64)
// ---------------------------------------------------------------------------
__global__ __launch_bounds__(256) void transpose_in(
    const void* __restrict__ src, const int* __restrict__ flag,
    u16* __restrict__ dst, int R, int C) {
  __shared__ float tile[64][65];
  const int f = *flag;
  const int tx = threadIdx.x & 63, ty = threadIdx.x >> 6;
  const long c0 = (long)blockIdx.x * 64, r0 = (long)blockIdx.y * 64;
#pragma unroll
  for (int i = 0; i < 16; i++) {
    const int r = ty + i * 4;
    tile[r][tx] = ldin(src, (r0 + r) * (long)C + c0 + tx, f);
  }
  __syncthreads();
#pragma unroll
  for (int i = 0; i < 16; i++) {
    const int cc = ty + i * 4;
    dst[(c0 + cc) * (long)R + r0 + tx] = f2bf(tile[tx][cc]);
  }
}

// concat 3 external bias vectors (len 1024 each) into one f32 [3072]
__global__ __launch_bounds__(256) void concat3(
    const void* __restrict__ a, const void* __restrict__ b,
    const void* __restrict__ c, const int* __restrict__ flag,
    float* __restrict__ out) {
  const int i = blockIdx.x * 256 + threadIdx.x;
  const int fl = *flag;
  if (i < 1024) out[i] = ldin(a, i, fl);
  else if (i < 2048) out[i] = ldin(b, i - 1024, fl);
  else if (i < 3072) out[i] = ldin(c, i - 2048, fl);
}

// ---------------------------------------------------------------------------
// LayerNorm over last dim (1024) -> bf16 out. One block per row.
// xmode: 0 = bf16 ws buffer, 1 = f32 ws buffer, 2 = external (per flag)
// ---------------------------------------------------------------------------
__global__ __launch_bounds__(256) void ln_kernel(
    const void* __restrict__ xin, int xmode, const int* __restrict__ flag,
    const void* __restrict__ w, const void* __restrict__ b,
    u16* __restrict__ out) {
  const long row = blockIdx.x;
  const int tid = threadIdx.x;
  const int fl = *flag;
  const int xf = (xmode == 2) ? fl : xmode;
  float v[4];
  if (xf) {
    const float4 q = ((const float4*)((const float*)xin + row * EE))[tid];
    v[0] = q.x; v[1] = q.y; v[2] = q.z; v[3] = q.w;
  } else {
    const ushort4 u = ((const ushort4*)((const u16*)xin + row * EE))[tid];
    v[0] = bf2f(u.x); v[1] = bf2f(u.y); v[2] = bf2f(u.z); v[3] = bf2f(u.w);
  }
  float sum = v[0] + v[1] + v[2] + v[3];
  float sq = v[0] * v[0] + v[1] * v[1] + v[2] * v[2] + v[3] * v[3];
#pragma unroll
  for (int o = 32; o > 0; o >>= 1) {
    sum += __shfl_xor(sum, o);
    sq += __shfl_xor(sq, o);
  }
  __shared__ float s1[4], s2[4];
  const int wave = tid >> 6, lane = tid & 63;
  if (lane == 0) { s1[wave] = sum; s2[wave] = sq; }
  __syncthreads();
  sum = s1[0] + s1[1] + s1[2] + s1[3];
  sq = s2[0] + s2[1] + s2[2] + s2[3];
  const float mu = sum * (1.f / EE);
  const float var = sq * (1.f / EE) - mu * mu;
  const float rs = rsqrtf(var + 1e-5f);
  ushort4 o4;
  float r0 = (v[0] - mu) * rs * ldin(w, tid * 4 + 0, fl) + ldin(b, tid * 4 + 0, fl);
  float r1 = (v[1] - mu) * rs * ldin(w, tid * 4 + 1, fl) + ldin(b, tid * 4 + 1, fl);
  float r2 = (v[2] - mu) * rs * ldin(w, tid * 4 + 2, fl) + ldin(b, tid * 4 + 2, fl);
  float r3 = (v[3] - mu) * rs * ldin(w, tid * 4 + 3, fl) + ldin(b, tid * 4 + 3, fl);
  o4.x = f2bf(r0); o4.y = f2bf(r1); o4.z = f2bf(r2); o4.w = f2bf(r3);
  ((ushort4*)(out + row * EE))[tid] = o4;
}

// ---------------------------------------------------------------------------
// 256x256 8-wave multi-phase counted-vmcnt GEMM (T3+T4 regime, BK=32).
// 512 thr = 8 waves (2Mx4N), per-wave out 128x64 (acc 8x4 f32x4).
// LDS: 3 K-tile dbufs x {A,B} x 2 halves x [128][32] bf16 = 96 KiB.
// Per K-tile t (dbuf t%3), 2 phases:
//  P1: ds_read A-mq0(4xb128)+B all(4xb128); stage A halves of t+2;
//      vmcnt(4); s_barrier; setprio1; 16 MFMA (mi 0-3 x ni 0-3); setprio0; bar
//  P2: ds_read A-mq1; stage B halves of t+2; vmcnt(4); bar; 16 MFMA; bar
// Invariants: stage->consume gap >= 3 phases, vmcnt(4) guarantees >=2-phase-
// old stages landed; stage dbuf (t+2)%3 disjoint from read dbufs t%3,(t+1)%3.
// Tail: clamped dummy stages keep counts uniform; __syncthreads before
// epilogue drains everything. Row stride 64B -> frag ds_reads naturally
// bank-even (no swizzle needed at BK=32).
// act/resMode/outMode semantics identical to gemm128.
// ---------------------------------------------------------------------------
__global__ __launch_bounds__(512, 2) void gemm256(
    const u16* __restrict__ A, const u16* __restrict__ Bt,
    const void* __restrict__ bias, int biasF32,
    const void* __restrict__ res, int resMode,
    void* __restrict__ Cout, void* __restrict__ Cv, int outMode, long coff,
    const int* __restrict__ flag, int M, int N, int K, int act) {
  __shared__ u16 As[3][2][4096];  // [dbuf][half][128*32]
  __shared__ u16 Bs[3][2][4096];
  const int tid = threadIdx.x;
  const int lane = tid & 63;
  const int wave = tid >> 6;  // 0..7
  const int wr = wave >> 2;   // 0..1: A-half / output row block (128)
  const int wc = wave & 3;    // 0..3: output col block (64)
  const int quad = lane >> 4;
  const int l16 = lane & 15;
  // GROUP=4 supergroup on raw linear bid (L2 locality; robust to XCD map)
  const int bid0 = blockIdx.x + gridDim.x * blockIdx.y;
  const int width = 4 * gridDim.y;
  const int group = bid0 / width;
  const int rem = bid0 - group * width;
  const int bx = group * 4 + (rem & 3);
  const int by = rem >> 2;
  const long bm = (long)bx * 256;
  const long bn = (long)by * 256;

  f32x4 acc[8][4];
#pragma unroll
  for (int i = 0; i < 8; i++)
#pragma unroll
    for (int j = 0; j < 4; j++)
#pragma unroll
      for (int r = 0; r < 4; r++) acc[i][j][r] = 0.f;

  // staging: thread covers 16B unit U=tid of a [128][32] half-tile:
  // row U>>2, col-unit U&3. One async16 per thread per half.
  const int sr = tid >> 2;
  const int su = tid & 3;
  const u16* Ap = A + (bm + sr) * (long)K + su * 8;
  const u16* Bp = Bt + (bn + sr) * (long)K + su * 8;
  const long half128 = 128 * (long)K;

  auto stgA = [&](int d, int h, long kt) {
    async16(Ap + h * half128 + kt, &As[d][h][0] + wave * 512);
  };
  auto stgB = [&](int d, int h, long kt) {
    async16(Bp + h * half128 + kt, &Bs[d][h][0] + wave * 512);
  };

  const int nt = K >> 5;
  // prologue: stage tiles 0,1 (8 loads); land tile 0, keep tile 1 in flight
  stgA(0, 0, 0); stgA(0, 1, 0); stgB(0, 0, 0); stgB(0, 1, 0);
  stgA(1, 0, 32); stgA(1, 1, 32); stgB(1, 0, 32); stgB(1, 1, 32);
  asm volatile("s_waitcnt vmcnt(4)" ::: "memory");
  __builtin_amdgcn_s_barrier();

  int d = 0;
  for (int t = 0; t < nt; ++t) {
    const int sd = (t + 2) % 3;
    const long skt = ((t + 2 < nt) ? (long)(t + 2) : (long)(nt - 1)) * 32;
    const u16* Ah = &As[d][wr][0];
    short8 af[4], bfr[4];
    // ---- phase 1: A-mq0 + all B frags; stage A halves of t+2
#pragma unroll
    for (int i = 0; i < 4; i++)
      af[i] = *(const short8*)&Ah[(i * 16 + l16) * 32 + quad * 8];
#pragma unroll
    for (int ni = 0; ni < 4; ni++) {
      const int cl = wc * 64 + ni * 16 + l16;  // 0..255 within B tile
      bfr[ni] = *(const short8*)&Bs[d][cl >> 7][(cl & 127) * 32 + quad * 8];
    }
    stgA(sd, 0, skt);
    stgA(sd, 1, skt);
    asm volatile("s_waitcnt vmcnt(4)" ::: "memory");
    __builtin_amdgcn_s_barrier();
    __builtin_amdgcn_s_setprio(1);
#pragma unroll
    for (int mi = 0; mi < 4; mi++)
#pragma unroll
      for (int ni = 0; ni < 4; ni++)
        acc[mi][ni] = __builtin_amdgcn_mfma_f32_16x16x32_bf16(
            af[mi], bfr[ni], acc[mi][ni], 0, 0, 0);
    __builtin_amdgcn_s_setprio(0);
    __builtin_amdgcn_s_barrier();
    // ---- phase 2: A-mq1 (reuse B regs); stage B halves of t+2
#pragma unroll
    for (int i = 0; i < 4; i++)
      af[i] = *(const short8*)&Ah[(64 + i * 16 + l16) * 32 + quad * 8];
    stgB(sd, 0, skt);
    stgB(sd, 1, skt);
    asm volatile("s_waitcnt vmcnt(4)" ::: "memory");
    __builtin_amdgcn_s_barrier();
    __builtin_amdgcn_s_setprio(1);
#pragma unroll
    for (int mi = 0; mi < 4; mi++)
#pragma unroll
      for (int ni = 0; ni < 4; ni++)
        acc[4 + mi][ni] = __builtin_amdgcn_mfma_f32_16x16x32_bf16(
            af[mi], bfr[ni], acc[4 + mi][ni], 0, 0, 0);
    __builtin_amdgcn_s_setprio(0);
    __builtin_amdgcn_s_barrier();
    d = (d == 2) ? 0 : d + 1;
  }
  __syncthreads();  // full drain (incl. tail dummies) before LDS reuse

  // ---- epilogue: bias+act, per-wave LDS transpose, coalesced 16B stores
  const int fl = *flag;
  const long Nl = N;
  float bv4[4];
  long gcA[4];
#pragma unroll
  for (int ni = 0; ni < 4; ni++) {
    gcA[ni] = bn + wc * 64 + ni * 16 + l16;
    bv4[ni] = biasF32 ? ((const float*)bias)[gcA[ni]] : ldin(bias, gcA[ni], fl);
  }
#pragma unroll
  for (int mi = 0; mi < 8; mi++)
#pragma unroll
    for (int ni = 0; ni < 4; ni++)
#pragma unroll
      for (int r = 0; r < 4; r++) {
        float v = acc[mi][ni][r] + bv4[ni];
        if (act == 1 || (act == 3 && gcA[ni] < 2048)) v = fmaxf(v, 0.f);
        else if (act == 2) v = 0.5f * v * (1.f + erff(v * 0.70710678118654752f));
        acc[mi][ni][r] = v;
      }
  float* sf = (float*)&As[0][0][0] + wave * 1088;  // 16x68 slab per wave
  const int er = lane >> 2;        // 0..15 row in slab
  const int ec = (lane & 3) * 16;  // 16-col run within wave's 64 cols
#pragma unroll
  for (int mi = 0; mi < 8; mi++) {
#pragma unroll
    for (int ni = 0; ni < 4; ni++)
#pragma unroll
      for (int r = 0; r < 4; r++)
        sf[(quad * 4 + r) * 68 + ni * 16 + l16] = acc[mi][ni][r];
    // same-wave DS ops are in-order => write-then-read safe per wave
    f32x4 w0 = *(const f32x4*)&sf[er * 68 + ec + 0];
    f32x4 w1 = *(const f32x4*)&sf[er * 68 + ec + 4];
    f32x4 w2 = *(const f32x4*)&sf[er * 68 + ec + 8];
    f32x4 w3 = *(const f32x4*)&sf[er * 68 + ec + 12];
    const long gr = bm + wr * 128 + mi * 16 + er;
    const long gc0 = bn + wc * 64 + ec;
    const long ib = gr * Nl + gc0;
    if (resMode == 1 || (resMode == 2 && fl)) {
      const f32x4* rp = (const f32x4*)((const float*)res + ib);
      f32x4 r0 = rp[0], r1 = rp[1], r2 = rp[2], r3 = rp[3];
#pragma unroll
      for (int j = 0; j < 4; j++) {
        w0[j] += r0[j]; w1[j] += r1[j]; w2[j] += r2[j]; w3[j] += r3[j];
      }
    } else if (resMode == 2) {
      const short8* rp = (const short8*)((const u16*)res + ib);
      short8 ra = rp[0], rb = rp[1];
#pragma unroll
      for (int j = 0; j < 4; j++) {
        w0[j] += bf2f((u16)ra[j]);
        w1[j] += bf2f((u16)ra[j + 4]);
        w2[j] += bf2f((u16)rb[j]);
        w3[j] += bf2f((u16)rb[j + 4]);
      }
    }
    if (outMode == 1 || (outMode == 2 && fl)) {
      f32x4* op = (f32x4*)((float*)Cout + coff + ib);
      op[0] = w0; op[1] = w1; op[2] = w2; op[3] = w3;
    } else {
      u16 tmp[16];
#pragma unroll
      for (int j = 0; j < 4; j++) {
        tmp[j] = f2bf(w0[j]);
        tmp[j + 4] = f2bf(w1[j]);
        tmp[j + 8] = f2bf(w2[j]);
        tmp[j + 12] = f2bf(w3[j]);
      }
      u16* op;
      if (outMode == 3) {
        const int plane = (int)(gc0 >> 10);
        u16* dst = (plane == 2) ? (u16*)Cv
                                : ((u16*)Cout + plane * ((long)M << 10));
        op = dst + (gr << 10) + (gc0 & 1023);
      } else {
        op = (u16*)Cout + coff + ib;
      }
      *(short8*)op = *(short8*)&tmp[0];
      *(short8*)(op + 8) = *(short8*)&tmp[8];
    }
  }
}

// ---------------------------------------------------------------------------
// 128x128 counted-vmcnt GEMM (round-4 proven) — used for proj (N=1024,
// 512 blocks; 256-tile would leave half the GPU idle).
// ---------------------------------------------------------------------------
__global__ __launch_bounds__(256, 3) void gemm_bf16(
    const u16* __restrict__ A, const u16* __restrict__ Bt,
    const void* __restrict__ bias, int biasF32,
    const void* __restrict__ res, int resMode,
    void* __restrict__ Cout, void* __restrict__ Cv, int outMode, long coff,
    const int* __restrict__ flag, int M, int N, int K, int act) {
  __shared__ u16 As[3][4096];
  __shared__ u16 Bs[3][4096];
  const int tid = threadIdx.x;
  const int lane = tid & 63;
  const int wave = tid >> 6;
  const int quad = lane >> 4;
  const int l16 = lane & 15;
  const int wm = (wave >> 1) * 64;
  const int wn = (wave & 1) * 64;
  const int bid0 = blockIdx.x + gridDim.x * blockIdx.y;
  const int gy = gridDim.y;
  const int width = 8 * gy;
  const int group = bid0 / width;
  const int rem = bid0 - group * width;
  const int bx = group * 8 + (rem & 7);
  const int by = rem >> 3;
  const long bm = (long)bx * 128;
  const long bn = (long)by * 128;

  f32x4 acc[4][4];
#pragma unroll
  for (int i = 0; i < 4; i++)
#pragma unroll
    for (int j = 0; j < 4; j++)
#pragma unroll
      for (int r = 0; r < 4; r++) acc[i][j][r] = 0.f;

  const int trow = tid >> 2;
  const int tswz = (tid & 3) ^ (trow & 3);
  const u16* Ap = A + (bm + trow) * (long)K + tswz * 8;
  const u16* Bp = Bt + (bn + trow) * (long)K + tswz * 8;
  const long rowK64 = 64 * (long)K;

  auto stage = [&](int buf, long kt) {
    u16* Ad = &As[buf][wave * 512];
    u16* Bd = &Bs[buf][wave * 512];
    async16(Ap + kt, Ad);
    async16(Ap + rowK64 + kt, Ad + 2048);
    async16(Bp + kt, Bd);
    async16(Bp + rowK64 + kt, Bd + 2048);
  };
  const int rswz = (quad ^ (l16 & 3)) * 8;
  auto compute = [&](int buf) {
    short8 af[4], bfr[4];
#pragma unroll
    for (int i = 0; i < 4; i++)
      af[i] = *(const short8*)&As[buf][(wm + i * 16 + l16) * 32 + rswz];
#pragma unroll
    for (int i = 0; i < 4; i++)
      bfr[i] = *(const short8*)&Bs[buf][(wn + i * 16 + l16) * 32 + rswz];
    __builtin_amdgcn_s_setprio(1);
#pragma unroll
    for (int mi = 0; mi < 4; mi++)
#pragma unroll
      for (int ni = 0; ni < 4; ni++)
        acc[mi][ni] = __builtin_amdgcn_mfma_f32_16x16x32_bf16(
            af[mi], bfr[ni], acc[mi][ni], 0, 0, 0);
    __builtin_amdgcn_s_setprio(0);
  };

  const int nt = K >> 5;
  stage(0, 0);
  stage(1, 32);
  asm volatile("s_waitcnt vmcnt(4)" ::: "memory");
  __builtin_amdgcn_s_barrier();
  int cb = 0, sb = 2;
  for (int t = 0; t < nt; ++t) {
    const long ts = (t + 2 < nt) ? (long)(t + 2) * 32 : (long)(nt - 1) * 32;
    stage(sb, ts);
    compute(cb);
    asm volatile("s_waitcnt vmcnt(4)" ::: "memory");
    __builtin_amdgcn_s_barrier();
    cb = (cb == 2) ? 0 : cb + 1;
    sb = (sb == 2) ? 0 : sb + 1;
  }
  __syncthreads();

  const int fl = *flag;
  const long Nl = N;
  float bv4[4];
  long gcA[4];
#pragma unroll
  for (int ni = 0; ni < 4; ni++) {
    gcA[ni] = bn + wn + ni * 16 + l16;
    bv4[ni] = biasF32 ? ((const float*)bias)[gcA[ni]] : ldin(bias, gcA[ni], fl);
  }
#pragma unroll
  for (int mi = 0; mi < 4; mi++)
#pragma unroll
    for (int ni = 0; ni < 4; ni++)
#pragma unroll
      for (int r = 0; r < 4; r++) {
        float v = acc[mi][ni][r] + bv4[ni];
        if (act == 1 || (act == 3 && gcA[ni] < 2048)) v = fmaxf(v, 0.f);
        else if (act == 2) v = 0.5f * v * (1.f + erff(v * 0.70710678118654752f));
        acc[mi][ni][r] = v;
      }
  float* sf = (float*)&As[0][0] + wave * 1088;
  const int er = lane >> 2;
  const int ec = (lane & 3) * 16;
#pragma unroll
  for (int mi = 0; mi < 4; mi++) {
#pragma unroll
    for (int ni = 0; ni < 4; ni++)
#pragma unroll
      for (int r = 0; r < 4; r++)
        sf[(quad * 4 + r) * 68 + ni * 16 + l16] = acc[mi][ni][r];
    f32x4 w0 = *(const f32x4*)&sf[er * 68 + ec + 0];
    f32x4 w1 = *(const f32x4*)&sf[er * 68 + ec + 4];
    f32x4 w2 = *(const f32x4*)&sf[er * 68 + ec + 8];
    f32x4 w3 = *(const f32x4*)&sf[er * 68 + ec + 12];
    const long gr = bm + wm + mi * 16 + er;
    const long gc0 = bn + wn + ec;
    const long ib = gr * Nl + gc0;
    if (resMode == 1 || (resMode == 2 && fl)) {
      const f32x4* rp = (const f32x4*)((const float*)res + ib);
      f32x4 r0 = rp[0], r1 = rp[1], r2 = rp[2], r3 = rp[3];
#pragma unroll
      for (int j = 0; j < 4; j++) {
        w0[j] += r0[j]; w1[j] += r1[j]; w2[j] += r2[j]; w3[j] += r3[j];
      }
    } else if (resMode == 2) {
      const short8* rp = (const short8*)((const u16*)res + ib);
      short8 ra = rp[0], rb = rp[1];
#pragma unroll
      for (int j = 0; j < 4; j++) {
        w0[j] += bf2f((u16)ra[j]);
        w1[j] += bf2f((u16)ra[j + 4]);
        w2[j] += bf2f((u16)rb[j]);
        w3[j] += bf2f((u16)rb[j + 4]);
      }
    }
    if (outMode == 1 || (outMode == 2 && fl)) {
      f32x4* op = (f32x4*)((float*)Cout + coff + ib);
      op[0] = w0; op[1] = w1; op[2] = w2; op[3] = w3;
    } else {
      u16 tmp[16];
#pragma unroll
      for (int j = 0; j < 4; j++) {
        tmp[j] = f2bf(w0[j]);
        tmp[j + 4] = f2bf(w1[j]);
        tmp[j + 8] = f2bf(w2[j]);
        tmp[j + 12] = f2bf(w3[j]);
      }
      u16* op;
      if (outMode == 3) {
        const int plane = (int)(bn >> 10);
        u16* dst = (plane == 2) ? (u16*)Cv
                                : ((u16*)Cout + plane * ((long)M << 10));
        op = dst + (gr << 10) + (gc0 & 1023);
      } else {
        op = (u16*)Cout + coff + ib;
      }
      *(short8*)op = *(short8*)&tmp[0];
      *(short8*)(op + 8) = *(short8*)&tmp[8];
    }
  }
}

// ---------------------------------------------------------------------------
// kv partial: per (bh, chunk) accumulate kv_s/kv_c [64x64], ksum_s/c [64]
// kvpart[ch][bh][2][64][64], kspart[ch][bh][2][64]
// ---------------------------------------------------------------------------
__global__ __launch_bounds__(256) void kv_partial(
    const u16* __restrict__ k, const u16* __restrict__ v,
    float* __restrict__ kvpart, float* __restrict__ kspart) {
  const int bh = blockIdx.x;  // 0..63
  const int ch = blockIdx.y;  // 0..NCH-1
  const int b = bh >> 4, h = bh & 15;
  const int tid = threadIdx.x;
  __shared__ float kl[8][64], vl[8][64];
  const int dkq = tid >> 4;  // 0..15
  const int dvq = tid & 15;  // 0..15
  float accS[4][4] = {}, accC[4][4] = {};
  float ksS[4] = {}, ksC[4] = {};
  const int tt = tid >> 5;        // 0..7
  const int cc = (tid & 31) * 2;  // 0..62
  const long base = ((long)b * 4096 + ch * CHT) * EE + h * 64;
  for (int tb = 0; tb < CHT; tb += 8) {
    const long roff = base + (long)(tb + tt) * EE + cc;
    const unsigned int ku = *(const unsigned int*)(k + roff);
    const unsigned int vu = *(const unsigned int*)(v + roff);
    __syncthreads();
    kl[tt][cc] = bf2f((u16)ku);
    kl[tt][cc + 1] = bf2f((u16)(ku >> 16));
    vl[tt][cc] = bf2f((u16)vu);
    vl[tt][cc + 1] = bf2f((u16)(vu >> 16));
    __syncthreads();
#pragma unroll
    for (int j = 0; j < 8; j++) {
      const int t = ch * CHT + tb + j;
      float s, c;
      __sincosf((float)(t + 1) * (PI_F * 0.5f / 4096.f), &s, &c);
      float kk[4], vv[4];
#pragma unroll
      for (int i = 0; i < 4; i++) {
        kk[i] = kl[j][dkq * 4 + i];
        vv[i] = vl[j][dvq * 4 + i];
      }
#pragma unroll
      for (int i = 0; i < 4; i++) {
        const float ks_ = kk[i] * s, kc_ = kk[i] * c;
        ksS[i] += ks_;
        ksC[i] += kc_;
#pragma unroll
        for (int jj = 0; jj < 4; jj++) {
          accS[i][jj] += ks_ * vv[jj];
          accC[i][jj] += kc_ * vv[jj];
        }
      }
    }
  }
  float* outS = kvpart + (((long)ch * 64 + bh) * 2 + 0) * 4096;
  float* outC = outS + 4096;
#pragma unroll
  for (int i = 0; i < 4; i++)
#pragma unroll
    for (int jj = 0; jj < 4; jj++) {
      outS[(dkq * 4 + i) * 64 + dvq * 4 + jj] = accS[i][jj];
      outC[(dkq * 4 + i) * 64 + dvq * 4 + jj] = accC[i][jj];
    }
  if (dvq == 0) {
    float* oS = kspart + ((long)ch * 64 + bh) * 2 * 64;
#pragma unroll
    for (int i = 0; i < 4; i++) {
      oS[dkq * 4 + i] = ksS[i];
      oS[64 + dkq * 4 + i] = ksC[i];
    }
  }
}

// ---------------------------------------------------------------------------
__global__ __launch_bounds__(256) void kv_reduce(
    const float* __restrict__ kvpart, const float* __restrict__ kspart,
    float* __restrict__ kvcomb, float* __restrict__ kscomb) {
  const long KVTOT = 64L * 2 * 4096;  // 524288
  const long KSTOT = 64L * 2 * 64;    // 8192
  const long idx = (long)blockIdx.x * 256 + threadIdx.x;
  if (idx < KVTOT) {
    float s = 0.f;
#pragma unroll
    for (int chn = 0; chn < NCH; chn++) s += kvpart[chn * KVTOT + idx];
    kvcomb[idx] = s;
  } else {
    const long i2 = idx - KVTOT;
    if (i2 < KSTOT) {
      float s = 0.f;
#pragma unroll
      for (int chn = 0; chn < NCH; chn++) s += kspart[chn * KSTOT + i2];
      kscomb[i2] = s;
    }
  }
}

// ---------------------------------------------------------------------------
// apply: out[t,dv] = (s_t*(q.KVs)+c_t*(q.KVc))[dv] / max(s_t*q.kss+c_t*q.ksc,eps)
// ---------------------------------------------------------------------------
__global__ __launch_bounds__(256) void attn_apply(
    const u16* __restrict__ q, const float* __restrict__ kvcomb,
    const float* __restrict__ kscomb, u16* __restrict__ attn) {
  const int bh = blockIdx.x;
  const int b = bh >> 4, h = bh & 15;
  const int t0 = blockIdx.y * 64;
  const int tid = threadIdx.x;
  __shared__ float kvl[2][64][64];
  __shared__ float ksl[2][64];
  __shared__ float ql[64][66];

  const float4* kvsrc = (const float4*)(kvcomb + (long)bh * 8192);
  float4* kvdst = (float4*)&kvl[0][0][0];
#pragma unroll
  for (int i = 0; i < 8; i++) kvdst[tid + 256 * i] = kvsrc[tid + 256 * i];
  if (tid < 32) ((float4*)&ksl[0][0])[tid] = ((const float4*)(kscomb + (long)bh * 128))[tid];
  {
    const int r = tid >> 2;
    const int c = (tid & 3) * 16;
    const u16* qp = q + ((long)b * 4096 + t0 + r) * EE + h * 64 + c;
    const uint4 u0 = *(const uint4*)qp;
    const uint4 u1 = *(const uint4*)(qp + 8);
    unsigned int uu[8] = {u0.x, u0.y, u0.z, u0.w, u1.x, u1.y, u1.z, u1.w};
#pragma unroll
    for (int i = 0; i < 8; i++) {
      ql[r][c + 2 * i] = bf2f((u16)uu[i]);
      ql[r][c + 2 * i + 1] = bf2f((u16)(uu[i] >> 16));
    }
  }
  __syncthreads();

  const int tg = tid >> 4;
  const int dvq = tid & 15;
  const int dv0 = dvq * 4;

  float o1[4][4] = {}, o2[4][4] = {}, zs[4] = {}, zc[4] = {};
  for (int dk = 0; dk < 64; dk++) {
    const float ks0 = ksl[0][dk], ks1 = ksl[1][dk];
    float kv0[4], kv1[4];
#pragma unroll
    for (int j = 0; j < 4; j++) {
      kv0[j] = kvl[0][dk][dv0 + j];
      kv1[j] = kvl[1][dk][dv0 + j];
    }
#pragma unroll
    for (int it = 0; it < 4; it++) {
      const float qv = ql[tg + it * 16][dk];
      zs[it] += qv * ks0;
      zc[it] += qv * ks1;
#pragma unroll
      for (int j = 0; j < 4; j++) {
        o1[it][j] += qv * kv0[j];
        o2[it][j] += qv * kv1[j];
      }
    }
  }
#pragma unroll
  for (int it = 0; it < 4; it++) {
    const int t = t0 + tg + it * 16;
    float s, c;
    __sincosf((float)(t + 1) * (PI_F * 0.5f / 4096.f), &s, &c);
    const float z = s * zs[it] + c * zc[it];
    const float zinv = 1.f / fmaxf(z, 1e-6f);
    ushort4 o4;
    o4.x = f2bf((s * o1[it][0] + c * o2[it][0]) * zinv);
    o4.y = f2bf((s * o1[it][1] + c * o2[it][1]) * zinv);
    o4.z = f2bf((s * o1[it][2] + c * o2[it][2]) * zinv);
    o4.w = f2bf((s * o1[it][3] + c * o2[it][3]) * zinv);
    *(ushort4*)(attn + ((long)b * 4096 + t) * EE + h * 64 + dv0) = o4;
  }
}

// ---------------------------------------------------------------------------
extern "C" void kernel_launch(void* const* d_in, const int* in_sizes, int n_in,
                              void* d_out, int out_size, void* d_ws, size_t ws_size,
                              hipStream_t stream) {
  const void* x = d_in[0];
  const void* ln1w = d_in[1];
  const void* ln1b = d_in[2];
  const void* wq = d_in[3];
  const void* bq = d_in[4];
  const void* wk = d_in[5];
  const void* bk = d_in[6];
  const void* wv = d_in[7];
  const void* bv = d_in[8];
  const void* wo = d_in[9];
  const void* bo = d_in[10];
  const void* ln2w = d_in[11];
  const void* ln2b = d_in[12];
  const void* wfc = d_in[13];
  const void* bfc = d_in[14];
  const void* wproj = d_in[15];
  const void* bproj = d_in[16];

  char* ws = (char*)d_ws;
  size_t off = 0;
  auto alloc = [&](size_t bytes) -> char* {
    char* p = ws + off;
    off += (bytes + 255) & ~((size_t)255);
    return p;
  };
  // footprint identical to the proven 202-MiB baseline layout
  int* flag = (int*)alloc(256);
  u16* wqkvT = (u16*)alloc((size_t)3 * EE * EE * 2);  // [wq^T|wk^T|wv^T] rows
  u16* woT = (u16*)alloc((size_t)EE * EE * 2);
  u16* wfcT = (u16*)alloc((size_t)EE * FF * 2);
  u16* wprojT = (u16*)alloc((size_t)FF * EE * 2);
  float* qkvBias = (float*)alloc(3072 * 4);
  u16* h = (u16*)alloc((size_t)MT * EE * 2);       // 32 MiB
  float* x2 = (float*)alloc((size_t)MT * EE * 4);  // 64 MiB (residual, f32)
  u16* qk2 = (u16*)alloc((size_t)2 * MT * EE * 2); // 64 MiB: q,k planes
  float* kvpart = (float*)alloc((size_t)NCH * 64 * 2 * 64 * 64 * 4);
  float* kspart = (float*)alloc((size_t)NCH * 64 * 2 * 64 * 4);
  float* kvcomb = (float*)alloc((size_t)64 * 2 * 64 * 64 * 4);
  float* kscomb = (float*)alloc((size_t)64 * 2 * 64 * 4);
  const long PL = (long)MT * EE;  // plane stride (elems)
  u16* qb = qk2;            // plane 0
  u16* kb = qk2 + PL;       // plane 1
  u16* vb = (u16*)x2;       // v plane aliases x2[0:32MiB] — x2 dead until WO
                            // gemm, v dead before WO gemm overwrites it
  u16* attnb = kb;          // k-plane dead after kv_partial
  u16* g = qk2;             // q+k planes (64 MiB) dead after WO gemm
  (void)ws_size; (void)in_sizes; (void)n_in; (void)out_size;

  detect_dtype<<<1, 256, 0, stream>>>((const u16*)x, flag);

  transpose_in<<<dim3(16, 16), 256, 0, stream>>>(wq, flag, wqkvT, EE, EE);
  transpose_in<<<dim3(16, 16), 256, 0, stream>>>(wk, flag, wqkvT + (size_t)EE * EE, EE, EE);
  transpose_in<<<dim3(16, 16), 256, 0, stream>>>(wv, flag, wqkvT + (size_t)2 * EE * EE, EE, EE);
  transpose_in<<<dim3(16, 16), 256, 0, stream>>>(wo, flag, woT, EE, EE);
  transpose_in<<<dim3(64, 16), 256, 0, stream>>>(wfc, flag, wfcT, EE, FF);
  transpose_in<<<dim3(16, 64), 256, 0, stream>>>(wproj, flag, wprojT, FF, EE);
  concat3<<<12, 256, 0, stream>>>(bq, bk, bv, flag, qkvBias);

  ln_kernel<<<MT, 256, 0, stream>>>(x, 2, flag, ln1w, ln1b, h);

  // fused QKV: N=3072, relu on q,k planes only; plane-major output
  gemm256<<<dim3(64, 12), 512, 0, stream>>>(h, wqkvT, qkvBias, 1, nullptr, 0,
                                            qk2, vb, 3, 0, flag, MT, 3072, EE, 3);

  kv_partial<<<dim3(64, NCH), 256, 0, stream>>>(kb, vb, kvpart, kspart);
  kv_reduce<<<2080, 256, 0, stream>>>(kvpart, kspart, kvcomb, kscomb);
  attn_apply<<<dim3(64, 64), 256, 0, stream>>>(qb, kvcomb, kscomb, attnb);

  gemm256<<<dim3(64, 4), 512, 0, stream>>>(attnb, woT, bo, 0, x, 2, x2, nullptr,
                                           1, 0, flag, MT, EE, EE, 0);
  ln_kernel<<<MT, 256, 0, stream>>>(x2, 1, flag, ln2w, ln2b, h);

  for (int c = 0; c < 2; c++) {
    const long ro = (long)c * 8192 * EE;
    gemm256<<<dim3(32, 16), 512, 0, stream>>>(h + ro, wfcT, bfc, 0, nullptr, 0,
                                              g, nullptr, 0, 0, flag, 8192, FF, EE, 2);
    gemm_bf16<<<dim3(64, 8), 256, 0, stream>>>(g, wprojT, bproj, 0, x2 + ro, 1,
                                               d_out, nullptr, 2, ro, flag, 8192, EE, FF, 0);
  }
}

// Round 7
// 1094.005 us; speedup vs baseline: 1.0489x; 1.0489x over previous
//
#include <hip/hip_runtime.h>

#define PI_F 3.14159265358979f
#define MT 16384   // B*T
#define EE 1024    // E
#define FF 4096    // 4E
#define NCH 8      // T-chunks for kv partial reduction
#define CHT (4096 / NCH)

typedef unsigned short u16;
typedef __attribute__((ext_vector_type(8))) short short8;
typedef __attribute__((ext_vector_type(4))) float f32x4;

__device__ __forceinline__ float bf2f(u16 u) {
  unsigned int v = ((unsigned int)u) << 16;
  float f;
  __builtin_memcpy(&f, &v, 4);
  return f;
}
__device__ __forceinline__ u16 f2bf(float f) {
  unsigned int x;
  __builtin_memcpy(&x, &f, 4);
  unsigned int r = x + 0x7fffu + ((x >> 16) & 1u);
  return (u16)(r >> 16);
}
// load element i from an external buffer whose dtype is runtime-detected
__device__ __forceinline__ float ldin(const void* p, long i, int f32) {
  return f32 ? ((const float*)p)[i] : bf2f(((const u16*)p)[i]);
}
// async global->LDS, 16B/lane; LDS dest = wave-uniform base + lane*16B
__device__ __forceinline__ void async16(const u16* g, u16* l) {
  __builtin_amdgcn_global_load_lds(
      (const __attribute__((address_space(1))) unsigned int*)g,
      (__attribute__((address_space(3))) unsigned int*)l, 16, 0, 0);
}

// ---------------------------------------------------------------------------
// dtype probe: bf16 N(0,1) data has no extreme-exponent u16s; fp32 data's low
// mantissa halves are ~uniform u16s -> ~45% extreme. flag: 0=bf16, 1=fp32.
// ---------------------------------------------------------------------------
__global__ __launch_bounds__(256) void detect_dtype(const u16* __restrict__ x,
                                                    int* __restrict__ flag) {
  const int tid = threadIdx.x;
  int cnt = 0;
  for (int i = tid; i < 2048; i += 256) {
    const int e = (x[i] >> 7) & 0xFF;
    if (e == 0 || e >= 0x90) cnt++;
  }
#pragma unroll
  for (int o = 32; o > 0; o >>= 1) cnt += __shfl_xor(cnt, o);
  __shared__ int s[4];
  if ((tid & 63) == 0) s[tid >> 6] = cnt;
  __syncthreads();
  if (tid == 0) flag[0] = (s[0] + s[1] + s[2] + s[3] > 200) ? 1 : 0;
}

// ---------------------------------------------------------------------------
// transpose + convert external weight: src[R][C] (bf16/f32 per flag) ->
// dst[C][R] bf16. block 256, grid (C/64, R/64)
// ---------------------------------------------------------------------------
__global__ __launch_bounds__(256) void transpose_in(
    const void* __restrict__ src, const int* __restrict__ flag,
    u16* __restrict__ dst, int R, int C) {
  __shared__ float tile[64][65];
  const int f = *flag;
  const int tx = threadIdx.x & 63, ty = threadIdx.x >> 6;
  const long c0 = (long)blockIdx.x * 64, r0 = (long)blockIdx.y * 64;
#pragma unroll
  for (int i = 0; i < 16; i++) {
    const int r = ty + i * 4;
    tile[r][tx] = ldin(src, (r0 + r) * (long)C + c0 + tx, f);
  }
  __syncthreads();
#pragma unroll
  for (int i = 0; i < 16; i++) {
    const int cc = ty + i * 4;
    dst[(c0 + cc) * (long)R + r0 + tx] = f2bf(tile[tx][cc]);
  }
}

// concat 3 external bias vectors (len 1024 each) into one f32 [3072]
__global__ __launch_bounds__(256) void concat3(
    const void* __restrict__ a, const void* __restrict__ b,
    const void* __restrict__ c, const int* __restrict__ flag,
    float* __restrict__ out) {
  const int i = blockIdx.x * 256 + threadIdx.x;
  const int fl = *flag;
  if (i < 1024) out[i] = ldin(a, i, fl);
  else if (i < 2048) out[i] = ldin(b, i - 1024, fl);
  else if (i < 3072) out[i] = ldin(c, i - 2048, fl);
}

// ---------------------------------------------------------------------------
// LayerNorm over last dim (1024) -> bf16 out. One block per row.
// xmode: 0 = bf16 ws buffer, 1 = f32 ws buffer, 2 = external (per flag)
// ---------------------------------------------------------------------------
__global__ __launch_bounds__(256) void ln_kernel(
    const void* __restrict__ xin, int xmode, const int* __restrict__ flag,
    const void* __restrict__ w, const void* __restrict__ b,
    u16* __restrict__ out) {
  const long row = blockIdx.x;
  const int tid = threadIdx.x;
  const int fl = *flag;
  const int xf = (xmode == 2) ? fl : xmode;
  float v[4];
  if (xf) {
    const float4 q = ((const float4*)((const float*)xin + row * EE))[tid];
    v[0] = q.x; v[1] = q.y; v[2] = q.z; v[3] = q.w;
  } else {
    const ushort4 u = ((const ushort4*)((const u16*)xin + row * EE))[tid];
    v[0] = bf2f(u.x); v[1] = bf2f(u.y); v[2] = bf2f(u.z); v[3] = bf2f(u.w);
  }
  float sum = v[0] + v[1] + v[2] + v[3];
  float sq = v[0] * v[0] + v[1] * v[1] + v[2] * v[2] + v[3] * v[3];
#pragma unroll
  for (int o = 32; o > 0; o >>= 1) {
    sum += __shfl_xor(sum, o);
    sq += __shfl_xor(sq, o);
  }
  __shared__ float s1[4], s2[4];
  const int wave = tid >> 6, lane = tid & 63;
  if (lane == 0) { s1[wave] = sum; s2[wave] = sq; }
  __syncthreads();
  sum = s1[0] + s1[1] + s1[2] + s1[3];
  sq = s2[0] + s2[1] + s2[2] + s2[3];
  const float mu = sum * (1.f / EE);
  const float var = sq * (1.f / EE) - mu * mu;
  const float rs = rsqrtf(var + 1e-5f);
  ushort4 o4;
  float r0 = (v[0] - mu) * rs * ldin(w, tid * 4 + 0, fl) + ldin(b, tid * 4 + 0, fl);
  float r1 = (v[1] - mu) * rs * ldin(w, tid * 4 + 1, fl) + ldin(b, tid * 4 + 1, fl);
  float r2 = (v[2] - mu) * rs * ldin(w, tid * 4 + 2, fl) + ldin(b, tid * 4 + 2, fl);
  float r3 = (v[3] - mu) * rs * ldin(w, tid * 4 + 3, fl) + ldin(b, tid * 4 + 3, fl);
  o4.x = f2bf(r0); o4.y = f2bf(r1); o4.z = f2bf(r2); o4.w = f2bf(r3);
  ((ushort4*)(out + row * EE))[tid] = o4;
}

// ---------------------------------------------------------------------------
// 256x256 8-wave m201-style GEMM, BK=64, 4 phases/K-tile, counted vmcnt.
// LDS: 2 dbufs x 4 half-tiles [128][64] bf16 = 128 KiB. 8 waves (2Mx4N),
// per-wave C = 128x64; phase = {vmcnt(N); s_barrier; ds_reads; stage one
// half of tile t+1; setprio1; 16 MFMA; setprio0}. READS COME AFTER THE
// WAIT+BARRIER (round-6 had reads before the wait -> read garbage -> NaN).
// Wait derivation (2 loads per stage, uniform): entering p0 outstanding =
// A0,A1,B0,B1 of tile t = 8 -> vmcnt(2) lands A0,A1,B0 (p0 reads A+B0;
// leaves B1(t) in flight). p0 stages A0(t+1) -> 4. Entering p1 vmcnt(2)
// lands B1(t) (p1 reads it; leaves A0(t+1)). p1 stages A1(t+1) -> 4.
// p2/p3 read only landed halves -> barrier only; stage B0/B1(t+1) -> 8.
// Invariant closes: entering p0(t+1) outstanding = 8 again.
// Overwrite race: stages into dbuf sd issue only after p0(t)'s barrier,
// which every wave reaches after its tile-(t-1) reads of dbuf sd were
// consumed by MFMAs -> ordered. Tail: clamped dummy re-stages keep counts
// uniform; __syncthreads drains before LDS-reuse epilogue.
// T2 swizzle both-sides: LDS[r][u] = global[r][u^(r&7)] (pre-swizzled
// global source, linear LDS dest); reads use unit (ks*4+quad)^(R&7).
// act: 0 none, 1 relu, 2 gelu, 3 relu-if-col<2048 (fused qkv)
// resMode: 0 none, 1 f32 ws, 2 external (flag). outMode: 0 bf16 ws,
// 1 f32 ws, 2 external d_out at coff, 3 plane-major qkv (plane2 -> Cv).
// ---------------------------------------------------------------------------
__global__ __launch_bounds__(512, 2) void gemm256(
    const u16* __restrict__ A, const u16* __restrict__ Bt,
    const void* __restrict__ bias, int biasF32,
    const void* __restrict__ res, int resMode,
    void* __restrict__ Cout, void* __restrict__ Cv, int outMode, long coff,
    const int* __restrict__ flag, int M, int N, int K, int act) {
  __shared__ u16 L[2][4][8192];  // [dbuf][A0,A1,B0,B1][128*64]
  const int tid = threadIdx.x;
  const int lane = tid & 63;
  const int wave = tid >> 6;  // 0..7
  const int wr = wave >> 2;   // 0..1: row half (A0/A1), rows wr*128..+127
  const int wc = wave & 3;    // 0..3: 32-col lane within each strip
  const int quad = lane >> 4;
  const int l16 = lane & 15;
  // GROUP=4 supergroup on raw linear bid (L2 locality; robust to XCD map)
  const int bid0 = blockIdx.x + gridDim.x * blockIdx.y;
  const int width = 4 * gridDim.y;
  const int group = bid0 / width;
  const int rem = bid0 - group * width;
  const int bx = group * 4 + (rem & 3);
  const int by = rem >> 2;
  const long bm = (long)bx * 256;
  const long bn = (long)by * 256;

  f32x4 acc[8][4];  // [qm*4+mi][s*2+ni]
#pragma unroll
  for (int i = 0; i < 8; i++)
#pragma unroll
    for (int j = 0; j < 4; j++)
#pragma unroll
      for (int r = 0; r < 4; r++) acc[i][j][r] = 0.f;

  // staging: wave w, instr j covers slab rows (j*8+w)*8..+7 of a half-tile;
  // lane l -> row (l>>3), source 16B-unit pre-swizzled: (l&7)^(l>>3).
  const u16* Ap = A + (bm + (lane >> 3)) * (long)K + ((lane & 7) ^ (lane >> 3)) * 8;
  const u16* Bp = Bt + (bn + (lane >> 3)) * (long)K + ((lane & 7) ^ (lane >> 3)) * 8;

  auto stgA = [&](int dd, int h, long kt) {
#pragma unroll
    for (int j = 0; j < 2; j++)
      async16(Ap + ((long)h * 128 + (j * 8 + wave) * 8) * (long)K + kt,
              &L[dd][h][(j * 8 + wave) * 512]);
  };
  auto stgB = [&](int dd, int h, long kt) {
#pragma unroll
    for (int j = 0; j < 2; j++)
      async16(Bp + ((long)h * 128 + (j * 8 + wave) * 8) * (long)K + kt,
              &L[dd][2 + h][(j * 8 + wave) * 512]);
  };

  const int nt = K >> 6;
  // prologue: stage all 4 halves of tile 0 into dbuf 0 (8 loads in flight)
  stgA(0, 0, 0); stgA(0, 1, 0); stgB(0, 0, 0); stgB(0, 1, 0);

  for (int t = 0; t < nt; ++t) {
    const int d = t & 1, sd = d ^ 1;
    const long skt = (long)((t + 1 < nt) ? t + 1 : nt - 1) * 64;
    const u16* Ah = &L[d][wr][0];
    const u16* B0h = &L[d][2][0];
    const u16* B1h = &L[d][3][0];
    short8 a8[8], bf0[4], bf1[4];
    // ---- p0: wait A0,A1,B0(t); read A(q0)+B0; stage A0(t+1); MFMA q0xB0
    asm volatile("s_waitcnt vmcnt(2)" ::: "memory");
    __builtin_amdgcn_s_barrier();
#pragma unroll
    for (int ks = 0; ks < 2; ks++) {
#pragma unroll
      for (int mi = 0; mi < 4; mi++) {
        const int R = mi * 16 + l16;
        a8[ks * 4 + mi] =
            *(const short8*)&Ah[R * 64 + ((ks * 4 + quad) ^ (R & 7)) * 8];
      }
#pragma unroll
      for (int ni = 0; ni < 2; ni++) {
        const int R = wc * 32 + ni * 16 + l16;
        bf0[ks * 2 + ni] =
            *(const short8*)&B0h[R * 64 + ((ks * 4 + quad) ^ (R & 7)) * 8];
      }
    }
    stgA(sd, 0, skt);
    __builtin_amdgcn_s_setprio(1);
#pragma unroll
    for (int mi = 0; mi < 4; mi++)
#pragma unroll
      for (int ni = 0; ni < 2; ni++)
#pragma unroll
        for (int ks = 0; ks < 2; ks++)
          acc[mi][ni] = __builtin_amdgcn_mfma_f32_16x16x32_bf16(
              a8[ks * 4 + mi], bf0[ks * 2 + ni], acc[mi][ni], 0, 0, 0);
    __builtin_amdgcn_s_setprio(0);
    // ---- p1: wait B1(t); read B1; stage A1(t+1); MFMA q0xB1
    asm volatile("s_waitcnt vmcnt(2)" ::: "memory");
    __builtin_amdgcn_s_barrier();
#pragma unroll
    for (int ks = 0; ks < 2; ks++)
#pragma unroll
      for (int ni = 0; ni < 2; ni++) {
        const int R = wc * 32 + ni * 16 + l16;
        bf1[ks * 2 + ni] =
            *(const short8*)&B1h[R * 64 + ((ks * 4 + quad) ^ (R & 7)) * 8];
      }
    stgA(sd, 1, skt);
    __builtin_amdgcn_s_setprio(1);
#pragma unroll
    for (int mi = 0; mi < 4; mi++)
#pragma unroll
      for (int ni = 0; ni < 2; ni++)
#pragma unroll
        for (int ks = 0; ks < 2; ks++)
          acc[mi][2 + ni] = __builtin_amdgcn_mfma_f32_16x16x32_bf16(
              a8[ks * 4 + mi], bf1[ks * 2 + ni], acc[mi][2 + ni], 0, 0, 0);
    __builtin_amdgcn_s_setprio(0);
    // ---- p2: read A(q1) (landed since p0's wait); stage B0(t+1); MFMA q1xB0
    __builtin_amdgcn_s_barrier();
#pragma unroll
    for (int ks = 0; ks < 2; ks++)
#pragma unroll
      for (int mi = 0; mi < 4; mi++) {
        const int R = 64 + mi * 16 + l16;
        a8[ks * 4 + mi] =
            *(const short8*)&Ah[R * 64 + ((ks * 4 + quad) ^ (R & 7)) * 8];
      }
    stgB(sd, 0, skt);
    __builtin_amdgcn_s_setprio(1);
#pragma unroll
    for (int mi = 0; mi < 4; mi++)
#pragma unroll
      for (int ni = 0; ni < 2; ni++)
#pragma unroll
        for (int ks = 0; ks < 2; ks++)
          acc[4 + mi][ni] = __builtin_amdgcn_mfma_f32_16x16x32_bf16(
              a8[ks * 4 + mi], bf0[ks * 2 + ni], acc[4 + mi][ni], 0, 0, 0);
    __builtin_amdgcn_s_setprio(0);
    // ---- p3: all frags cached; stage B1(t+1); MFMA q1xB1
    __builtin_amdgcn_s_barrier();
    stgB(sd, 1, skt);
    __builtin_amdgcn_s_setprio(1);
#pragma unroll
    for (int mi = 0; mi < 4; mi++)
#pragma unroll
      for (int ni = 0; ni < 2; ni++)
#pragma unroll
        for (int ks = 0; ks < 2; ks++)
          acc[4 + mi][2 + ni] = __builtin_amdgcn_mfma_f32_16x16x32_bf16(
              a8[ks * 4 + mi], bf1[ks * 2 + ni], acc[4 + mi][2 + ni], 0, 0, 0);
    __builtin_amdgcn_s_setprio(0);
  }
  __syncthreads();  // drains vmcnt(0): tail dummies done before LDS reuse

  // ---- epilogue: bias+act, per-wave LDS transpose, coalesced 16B stores
  const int fl = *flag;
  const long Nl = N;
  float bv4[4];
  long gcA[4];
#pragma unroll
  for (int s = 0; s < 2; s++)
#pragma unroll
    for (int ni = 0; ni < 2; ni++) {
      gcA[s * 2 + ni] = bn + s * 128 + wc * 32 + ni * 16 + l16;
      bv4[s * 2 + ni] = biasF32 ? ((const float*)bias)[gcA[s * 2 + ni]]
                                : ldin(bias, gcA[s * 2 + ni], fl);
    }
#pragma unroll
  for (int rg = 0; rg < 8; rg++)
#pragma unroll
    for (int j = 0; j < 4; j++)
#pragma unroll
      for (int r = 0; r < 4; r++) {
        float v = acc[rg][j][r] + bv4[j];
        if (act == 1 || (act == 3 && gcA[j] < 2048)) v = fmaxf(v, 0.f);
        else if (act == 2) v = 0.5f * v * (1.f + erff(v * 0.70710678118654752f));
        acc[rg][j][r] = v;
      }
  float* sf = (float*)&L[0][0][0] + wave * 1088;  // 16x68 f32 slab per wave
  const int er = lane >> 2;        // 0..15 row in slab
  const int ec = (lane & 3) * 16;  // 16-col run; c<32 strip0, c>=32 strip1
#pragma unroll
  for (int rg = 0; rg < 8; rg++) {
#pragma unroll
    for (int s = 0; s < 2; s++)
#pragma unroll
      for (int ni = 0; ni < 2; ni++)
#pragma unroll
        for (int r = 0; r < 4; r++)
          sf[(quad * 4 + r) * 68 + s * 32 + ni * 16 + l16] = acc[rg][s * 2 + ni][r];
    // same-wave DS in-order => write-then-read safe per wave
    f32x4 w0 = *(const f32x4*)&sf[er * 68 + ec + 0];
    f32x4 w1 = *(const f32x4*)&sf[er * 68 + ec + 4];
    f32x4 w2 = *(const f32x4*)&sf[er * 68 + ec + 8];
    f32x4 w3 = *(const f32x4*)&sf[er * 68 + ec + 12];
    const long gr = bm + wr * 128 + rg * 16 + er;
    const int es = ec >> 5;
    const long gc0 = bn + es * 128 + wc * 32 + (ec & 31);
    const long ib = gr * Nl + gc0;
    if (resMode == 1 || (resMode == 2 && fl)) {
      const f32x4* rp = (const f32x4*)((const float*)res + ib);
      f32x4 r0 = rp[0], r1 = rp[1], r2 = rp[2], r3 = rp[3];
#pragma unroll
      for (int j = 0; j < 4; j++) {
        w0[j] += r0[j]; w1[j] += r1[j]; w2[j] += r2[j]; w3[j] += r3[j];
      }
    } else if (resMode == 2) {
      const short8* rp = (const short8*)((const u16*)res + ib);
      short8 ra = rp[0], rb = rp[1];
#pragma unroll
      for (int j = 0; j < 4; j++) {
        w0[j] += bf2f((u16)ra[j]);
        w1[j] += bf2f((u16)ra[j + 4]);
        w2[j] += bf2f((u16)rb[j]);
        w3[j] += bf2f((u16)rb[j + 4]);
      }
    }
    if (outMode == 1 || (outMode == 2 && fl)) {
      f32x4* op = (f32x4*)((float*)Cout + coff + ib);
      op[0] = w0; op[1] = w1; op[2] = w2; op[3] = w3;
    } else {
      u16 tmp[16];
#pragma unroll
      for (int j = 0; j < 4; j++) {
        tmp[j] = f2bf(w0[j]);
        tmp[j + 4] = f2bf(w1[j]);
        tmp[j + 8] = f2bf(w2[j]);
        tmp[j + 12] = f2bf(w3[j]);
      }
      u16* op;
      if (outMode == 3) {
        const int plane = (int)(gc0 >> 10);
        u16* dst = (plane == 2) ? (u16*)Cv
                                : ((u16*)Cout + plane * ((long)M << 10));
        op = dst + (gr << 10) + (gc0 & 1023);
      } else {
        op = (u16*)Cout + coff + ib;
      }
      *(short8*)op = *(short8*)&tmp[0];
      *(short8*)(op + 8) = *(short8*)&tmp[8];
    }
  }
}

// ---------------------------------------------------------------------------
// 128x128 counted-vmcnt GEMM (round-4 proven) — used for proj (N=1024).
// ---------------------------------------------------------------------------
__global__ __launch_bounds__(256, 3) void gemm_bf16(
    const u16* __restrict__ A, const u16* __restrict__ Bt,
    const void* __restrict__ bias, int biasF32,
    const void* __restrict__ res, int resMode,
    void* __restrict__ Cout, void* __restrict__ Cv, int outMode, long coff,
    const int* __restrict__ flag, int M, int N, int K, int act) {
  __shared__ u16 As[3][4096];
  __shared__ u16 Bs[3][4096];
  const int tid = threadIdx.x;
  const int lane = tid & 63;
  const int wave = tid >> 6;
  const int quad = lane >> 4;
  const int l16 = lane & 15;
  const int wm = (wave >> 1) * 64;
  const int wn = (wave & 1) * 64;
  const int bid0 = blockIdx.x + gridDim.x * blockIdx.y;
  const int gy = gridDim.y;
  const int width = 8 * gy;
  const int group = bid0 / width;
  const int rem = bid0 - group * width;
  const int bx = group * 8 + (rem & 7);
  const int by = rem >> 3;
  const long bm = (long)bx * 128;
  const long bn = (long)by * 128;

  f32x4 acc[4][4];
#pragma unroll
  for (int i = 0; i < 4; i++)
#pragma unroll
    for (int j = 0; j < 4; j++)
#pragma unroll
      for (int r = 0; r < 4; r++) acc[i][j][r] = 0.f;

  const int trow = tid >> 2;
  const int tswz = (tid & 3) ^ (trow & 3);
  const u16* Ap = A + (bm + trow) * (long)K + tswz * 8;
  const u16* Bp = Bt + (bn + trow) * (long)K + tswz * 8;
  const long rowK64 = 64 * (long)K;

  auto stage = [&](int buf, long kt) {
    u16* Ad = &As[buf][wave * 512];
    u16* Bd = &Bs[buf][wave * 512];
    async16(Ap + kt, Ad);
    async16(Ap + rowK64 + kt, Ad + 2048);
    async16(Bp + kt, Bd);
    async16(Bp + rowK64 + kt, Bd + 2048);
  };
  const int rswz = (quad ^ (l16 & 3)) * 8;
  auto compute = [&](int buf) {
    short8 af[4], bfr[4];
#pragma unroll
    for (int i = 0; i < 4; i++)
      af[i] = *(const short8*)&As[buf][(wm + i * 16 + l16) * 32 + rswz];
#pragma unroll
    for (int i = 0; i < 4; i++)
      bfr[i] = *(const short8*)&Bs[buf][(wn + i * 16 + l16) * 32 + rswz];
    __builtin_amdgcn_s_setprio(1);
#pragma unroll
    for (int mi = 0; mi < 4; mi++)
#pragma unroll
      for (int ni = 0; ni < 4; ni++)
        acc[mi][ni] = __builtin_amdgcn_mfma_f32_16x16x32_bf16(
            af[mi], bfr[ni], acc[mi][ni], 0, 0, 0);
    __builtin_amdgcn_s_setprio(0);
  };

  const int nt = K >> 5;
  stage(0, 0);
  stage(1, 32);
  asm volatile("s_waitcnt vmcnt(4)" ::: "memory");
  __builtin_amdgcn_s_barrier();
  int cb = 0, sb = 2;
  for (int t = 0; t < nt; ++t) {
    const long ts = (t + 2 < nt) ? (long)(t + 2) * 32 : (long)(nt - 1) * 32;
    stage(sb, ts);
    compute(cb);
    asm volatile("s_waitcnt vmcnt(4)" ::: "memory");
    __builtin_amdgcn_s_barrier();
    cb = (cb == 2) ? 0 : cb + 1;
    sb = (sb == 2) ? 0 : sb + 1;
  }
  __syncthreads();

  const int fl = *flag;
  const long Nl = N;
  float bv4[4];
  long gcA[4];
#pragma unroll
  for (int ni = 0; ni < 4; ni++) {
    gcA[ni] = bn + wn + ni * 16 + l16;
    bv4[ni] = biasF32 ? ((const float*)bias)[gcA[ni]] : ldin(bias, gcA[ni], fl);
  }
#pragma unroll
  for (int mi = 0; mi < 4; mi++)
#pragma unroll
    for (int ni = 0; ni < 4; ni++)
#pragma unroll
      for (int r = 0; r < 4; r++) {
        float v = acc[mi][ni][r] + bv4[ni];
        if (act == 1 || (act == 3 && gcA[ni] < 2048)) v = fmaxf(v, 0.f);
        else if (act == 2) v = 0.5f * v * (1.f + erff(v * 0.70710678118654752f));
        acc[mi][ni][r] = v;
      }
  float* sf = (float*)&As[0][0] + wave * 1088;
  const int er = lane >> 2;
  const int ec = (lane & 3) * 16;
#pragma unroll
  for (int mi = 0; mi < 4; mi++) {
#pragma unroll
    for (int ni = 0; ni < 4; ni++)
#pragma unroll
      for (int r = 0; r < 4; r++)
        sf[(quad * 4 + r) * 68 + ni * 16 + l16] = acc[mi][ni][r];
    f32x4 w0 = *(const f32x4*)&sf[er * 68 + ec + 0];
    f32x4 w1 = *(const f32x4*)&sf[er * 68 + ec + 4];
    f32x4 w2 = *(const f32x4*)&sf[er * 68 + ec + 8];
    f32x4 w3 = *(const f32x4*)&sf[er * 68 + ec + 12];
    const long gr = bm + wm + mi * 16 + er;
    const long gc0 = bn + wn + ec;
    const long ib = gr * Nl + gc0;
    if (resMode == 1 || (resMode == 2 && fl)) {
      const f32x4* rp = (const f32x4*)((const float*)res + ib);
      f32x4 r0 = rp[0], r1 = rp[1], r2 = rp[2], r3 = rp[3];
#pragma unroll
      for (int j = 0; j < 4; j++) {
        w0[j] += r0[j]; w1[j] += r1[j]; w2[j] += r2[j]; w3[j] += r3[j];
      }
    } else if (resMode == 2) {
      const short8* rp = (const short8*)((const u16*)res + ib);
      short8 ra = rp[0], rb = rp[1];
#pragma unroll
      for (int j = 0; j < 4; j++) {
        w0[j] += bf2f((u16)ra[j]);
        w1[j] += bf2f((u16)ra[j + 4]);
        w2[j] += bf2f((u16)rb[j]);
        w3[j] += bf2f((u16)rb[j + 4]);
      }
    }
    if (outMode == 1 || (outMode == 2 && fl)) {
      f32x4* op = (f32x4*)((float*)Cout + coff + ib);
      op[0] = w0; op[1] = w1; op[2] = w2; op[3] = w3;
    } else {
      u16 tmp[16];
#pragma unroll
      for (int j = 0; j < 4; j++) {
        tmp[j] = f2bf(w0[j]);
        tmp[j + 4] = f2bf(w1[j]);
        tmp[j + 8] = f2bf(w2[j]);
        tmp[j + 12] = f2bf(w3[j]);
      }
      u16* op;
      if (outMode == 3) {
        const int plane = (int)(bn >> 10);
        u16* dst = (plane == 2) ? (u16*)Cv
                                : ((u16*)Cout + plane * ((long)M << 10));
        op = dst + (gr << 10) + (gc0 & 1023);
      } else {
        op = (u16*)Cout + coff + ib;
      }
      *(short8*)op = *(short8*)&tmp[0];
      *(short8*)(op + 8) = *(short8*)&tmp[8];
    }
  }
}

// ---------------------------------------------------------------------------
// kv partial: per (bh, chunk) accumulate kv_s/kv_c [64x64], ksum_s/c [64]
// kvpart[ch][bh][2][64][64], kspart[ch][bh][2][64]
// ---------------------------------------------------------------------------
__global__ __launch_bounds__(256) void kv_partial(
    const u16* __restrict__ k, const u16* __restrict__ v,
    float* __restrict__ kvpart, float* __restrict__ kspart) {
  const int bh = blockIdx.x;  // 0..63
  const int ch = blockIdx.y;  // 0..NCH-1
  const int b = bh >> 4, h = bh & 15;
  const int tid = threadIdx.x;
  __shared__ float kl[8][64], vl[8][64];
  const int dkq = tid >> 4;  // 0..15
  const int dvq = tid & 15;  // 0..15
  float accS[4][4] = {}, accC[4][4] = {};
  float ksS[4] = {}, ksC[4] = {};
  const int tt = tid >> 5;        // 0..7
  const int cc = (tid & 31) * 2;  // 0..62
  const long base = ((long)b * 4096 + ch * CHT) * EE + h * 64;
  for (int tb = 0; tb < CHT; tb += 8) {
    const long roff = base + (long)(tb + tt) * EE + cc;
    const unsigned int ku = *(const unsigned int*)(k + roff);
    const unsigned int vu = *(const unsigned int*)(v + roff);
    __syncthreads();
    kl[tt][cc] = bf2f((u16)ku);
    kl[tt][cc + 1] = bf2f((u16)(ku >> 16));
    vl[tt][cc] = bf2f((u16)vu);
    vl[tt][cc + 1] = bf2f((u16)(vu >> 16));
    __syncthreads();
#pragma unroll
    for (int j = 0; j < 8; j++) {
      const int t = ch * CHT + tb + j;
      float s, c;
      __sincosf((float)(t + 1) * (PI_F * 0.5f / 4096.f), &s, &c);
      float kk[4], vv[4];
#pragma unroll
      for (int i = 0; i < 4; i++) {
        kk[i] = kl[j][dkq * 4 + i];
        vv[i] = vl[j][dvq * 4 + i];
      }
#pragma unroll
      for (int i = 0; i < 4; i++) {
        const float ks_ = kk[i] * s, kc_ = kk[i] * c;
        ksS[i] += ks_;
        ksC[i] += kc_;
#pragma unroll
        for (int jj = 0; jj < 4; jj++) {
          accS[i][jj] += ks_ * vv[jj];
          accC[i][jj] += kc_ * vv[jj];
        }
      }
    }
  }
  float* outS = kvpart + (((long)ch * 64 + bh) * 2 + 0) * 4096;
  float* outC = outS + 4096;
#pragma unroll
  for (int i = 0; i < 4; i++)
#pragma unroll
    for (int jj = 0; jj < 4; jj++) {
      outS[(dkq * 4 + i) * 64 + dvq * 4 + jj] = accS[i][jj];
      outC[(dkq * 4 + i) * 64 + dvq * 4 + jj] = accC[i][jj];
    }
  if (dvq == 0) {
    float* oS = kspart + ((long)ch * 64 + bh) * 2 * 64;
#pragma unroll
    for (int i = 0; i < 4; i++) {
      oS[dkq * 4 + i] = ksS[i];
      oS[64 + dkq * 4 + i] = ksC[i];
    }
  }
}

// ---------------------------------------------------------------------------
__global__ __launch_bounds__(256) void kv_reduce(
    const float* __restrict__ kvpart, const float* __restrict__ kspart,
    float* __restrict__ kvcomb, float* __restrict__ kscomb) {
  const long KVTOT = 64L * 2 * 4096;  // 524288
  const long KSTOT = 64L * 2 * 64;    // 8192
  const long idx = (long)blockIdx.x * 256 + threadIdx.x;
  if (idx < KVTOT) {
    float s = 0.f;
#pragma unroll
    for (int chn = 0; chn < NCH; chn++) s += kvpart[chn * KVTOT + idx];
    kvcomb[idx] = s;
  } else {
    const long i2 = idx - KVTOT;
    if (i2 < KSTOT) {
      float s = 0.f;
#pragma unroll
      for (int chn = 0; chn < NCH; chn++) s += kspart[chn * KSTOT + i2];
      kscomb[i2] = s;
    }
  }
}

// ---------------------------------------------------------------------------
// apply: out[t,dv] = (s_t*(q.KVs)+c_t*(q.KVc))[dv] / max(s_t*q.kss+c_t*q.ksc,eps)
// ---------------------------------------------------------------------------
__global__ __launch_bounds__(256) void attn_apply(
    const u16* __restrict__ q, const float* __restrict__ kvcomb,
    const float* __restrict__ kscomb, u16* __restrict__ attn) {
  const int bh = blockIdx.x;
  const int b = bh >> 4, h = bh & 15;
  const int t0 = blockIdx.y * 64;
  const int tid = threadIdx.x;
  __shared__ float kvl[2][64][64];
  __shared__ float ksl[2][64];
  __shared__ float ql[64][66];

  const float4* kvsrc = (const float4*)(kvcomb + (long)bh * 8192);
  float4* kvdst = (float4*)&kvl[0][0][0];
#pragma unroll
  for (int i = 0; i < 8; i++) kvdst[tid + 256 * i] = kvsrc[tid + 256 * i];
  if (tid < 32) ((float4*)&ksl[0][0])[tid] = ((const float4*)(kscomb + (long)bh * 128))[tid];
  {
    const int r = tid >> 2;
    const int c = (tid & 3) * 16;
    const u16* qp = q + ((long)b * 4096 + t0 + r) * EE + h * 64 + c;
    const uint4 u0 = *(const uint4*)qp;
    const uint4 u1 = *(const uint4*)(qp + 8);
    unsigned int uu[8] = {u0.x, u0.y, u0.z, u0.w, u1.x, u1.y, u1.z, u1.w};
#pragma unroll
    for (int i = 0; i < 8; i++) {
      ql[r][c + 2 * i] = bf2f((u16)uu[i]);
      ql[r][c + 2 * i + 1] = bf2f((u16)(uu[i] >> 16));
    }
  }
  __syncthreads();

  const int tg = tid >> 4;
  const int dvq = tid & 15;
  const int dv0 = dvq * 4;

  float o1[4][4] = {}, o2[4][4] = {}, zs[4] = {}, zc[4] = {};
  for (int dk = 0; dk < 64; dk++) {
    const float ks0 = ksl[0][dk], ks1 = ksl[1][dk];
    float kv0[4], kv1[4];
#pragma unroll
    for (int j = 0; j < 4; j++) {
      kv0[j] = kvl[0][dk][dv0 + j];
      kv1[j] = kvl[1][dk][dv0 + j];
    }
#pragma unroll
    for (int it = 0; it < 4; it++) {
      const float qv = ql[tg + it * 16][dk];
      zs[it] += qv * ks0;
      zc[it] += qv * ks1;
#pragma unroll
      for (int j = 0; j < 4; j++) {
        o1[it][j] += qv * kv0[j];
        o2[it][j] += qv * kv1[j];
      }
    }
  }
#pragma unroll
  for (int it = 0; it < 4; it++) {
    const int t = t0 + tg + it * 16;
    float s, c;
    __sincosf((float)(t + 1) * (PI_F * 0.5f / 4096.f), &s, &c);
    const float z = s * zs[it] + c * zc[it];
    const float zinv = 1.f / fmaxf(z, 1e-6f);
    ushort4 o4;
    o4.x = f2bf((s * o1[it][0] + c * o2[it][0]) * zinv);
    o4.y = f2bf((s * o1[it][1] + c * o2[it][1]) * zinv);
    o4.z = f2bf((s * o1[it][2] + c * o2[it][2]) * zinv);
    o4.w = f2bf((s * o1[it][3] + c * o2[it][3]) * zinv);
    *(ushort4*)(attn + ((long)b * 4096 + t) * EE + h * 64 + dv0) = o4;
  }
}

// ---------------------------------------------------------------------------
extern "C" void kernel_launch(void* const* d_in, const int* in_sizes, int n_in,
                              void* d_out, int out_size, void* d_ws, size_t ws_size,
                              hipStream_t stream) {
  const void* x = d_in[0];
  const void* ln1w = d_in[1];
  const void* ln1b = d_in[2];
  const void* wq = d_in[3];
  const void* bq = d_in[4];
  const void* wk = d_in[5];
  const void* bk = d_in[6];
  const void* wv = d_in[7];
  const void* bv = d_in[8];
  const void* wo = d_in[9];
  const void* bo = d_in[10];
  const void* ln2w = d_in[11];
  const void* ln2b = d_in[12];
  const void* wfc = d_in[13];
  const void* bfc = d_in[14];
  const void* wproj = d_in[15];
  const void* bproj = d_in[16];

  char* ws = (char*)d_ws;
  size_t off = 0;
  auto alloc = [&](size_t bytes) -> char* {
    char* p = ws + off;
    off += (bytes + 255) & ~((size_t)255);
    return p;
  };
  // footprint identical to the proven 202-MiB baseline layout
  int* flag = (int*)alloc(256);
  u16* wqkvT = (u16*)alloc((size_t)3 * EE * EE * 2);  // [wq^T|wk^T|wv^T] rows
  u16* woT = (u16*)alloc((size_t)EE * EE * 2);
  u16* wfcT = (u16*)alloc((size_t)EE * FF * 2);
  u16* wprojT = (u16*)alloc((size_t)FF * EE * 2);
  float* qkvBias = (float*)alloc(3072 * 4);
  u16* h = (u16*)alloc((size_t)MT * EE * 2);       // 32 MiB
  float* x2 = (float*)alloc((size_t)MT * EE * 4);  // 64 MiB (residual, f32)
  u16* qk2 = (u16*)alloc((size_t)2 * MT * EE * 2); // 64 MiB: q,k planes
  float* kvpart = (float*)alloc((size_t)NCH * 64 * 2 * 64 * 64 * 4);
  float* kspart = (float*)alloc((size_t)NCH * 64 * 2 * 64 * 4);
  float* kvcomb = (float*)alloc((size_t)64 * 2 * 64 * 64 * 4);
  float* kscomb = (float*)alloc((size_t)64 * 2 * 64 * 4);
  const long PL = (long)MT * EE;  // plane stride (elems)
  u16* qb = qk2;            // plane 0
  u16* kb = qk2 + PL;       // plane 1
  u16* vb = (u16*)x2;       // v plane aliases x2[0:32MiB] — x2 dead until WO
                            // gemm, v dead before WO gemm overwrites it
  u16* attnb = kb;          // k-plane dead after kv_partial
  u16* g = qk2;             // q+k planes (64 MiB) dead after WO gemm
  (void)ws_size; (void)in_sizes; (void)n_in; (void)out_size;

  detect_dtype<<<1, 256, 0, stream>>>((const u16*)x, flag);

  transpose_in<<<dim3(16, 16), 256, 0, stream>>>(wq, flag, wqkvT, EE, EE);
  transpose_in<<<dim3(16, 16), 256, 0, stream>>>(wk, flag, wqkvT + (size_t)EE * EE, EE, EE);
  transpose_in<<<dim3(16, 16), 256, 0, stream>>>(wv, flag, wqkvT + (size_t)2 * EE * EE, EE, EE);
  transpose_in<<<dim3(16, 16), 256, 0, stream>>>(wo, flag, woT, EE, EE);
  transpose_in<<<dim3(64, 16), 256, 0, stream>>>(wfc, flag, wfcT, EE, FF);
  transpose_in<<<dim3(16, 64), 256, 0, stream>>>(wproj, flag, wprojT, FF, EE);
  concat3<<<12, 256, 0, stream>>>(bq, bk, bv, flag, qkvBias);

  ln_kernel<<<MT, 256, 0, stream>>>(x, 2, flag, ln1w, ln1b, h);

  // fused QKV: N=3072, relu on q,k planes only; plane-major output
  gemm256<<<dim3(64, 12), 512, 0, stream>>>(h, wqkvT, qkvBias, 1, nullptr, 0,
                                            qk2, vb, 3, 0, flag, MT, 3072, EE, 3);

  kv_partial<<<dim3(64, NCH), 256, 0, stream>>>(kb, vb, kvpart, kspart);
  kv_reduce<<<2080, 256, 0, stream>>>(kvpart, kspart, kvcomb, kscomb);
  attn_apply<<<dim3(64, 64), 256, 0, stream>>>(qb, kvcomb, kscomb, attnb);

  gemm256<<<dim3(64, 4), 512, 0, stream>>>(attnb, woT, bo, 0, x, 2, x2, nullptr,
                                           1, 0, flag, MT, EE, EE, 0);
  ln_kernel<<<MT, 256, 0, stream>>>(x2, 1, flag, ln2w, ln2b, h);

  for (int c = 0; c < 2; c++) {
    const long ro = (long)c * 8192 * EE;
    gemm256<<<dim3(32, 16), 512, 0, stream>>>(h + ro, wfcT, bfc, 0, nullptr, 0,
                                              g, nullptr, 0, 0, flag, 8192, FF, EE, 2);
    gemm_bf16<<<dim3(64, 8), 256, 0, stream>>>(g, wprojT, bproj, 0, x2 + ro, 1,
                                               d_out, nullptr, 2, ro, flag, 8192, EE, FF, 0);
  }
}